// Round 3
// baseline (442.200 us; speedup 1.0000x reference)
//
#include <hip/hip_runtime.h>

// ---------------------------------------------------------------------------
// Transducer joint network, round 5 (= round 4 + lgkmcnt barrier guard):
//   stage1: he = enc @ W1e^T (1024x512), hd = dec @ W1d^T (256x512)  [bf16 MFMA]
//   hker : h[r,k] = tanh(he[r>>6,k] + hd[(r>>14)*64+(r&63),k] + b1[k]) -> bf16 (ws)
//   joint: out[r,v] = sum_k h[r,k]*W2[v,k] + b2[v]   (65536x1000, K=512)
//   Joint = counted-vmcnt deep pipeline (T3+T4+T5):
//     BM=256 BN=128 BK=64, 512 thr (8 waves 4Mx2N), LDS 128KB:
//     A triple-buffered (prefetch distance 2), B double-buffered (distance 1),
//     boundary wait = s_waitcnt vmcnt(4) (never 0 in main loop), one barrier
//     per K-tile, lgkmcnt(0) drained before each barrier (WAR guard: next
//     stage writes the buffer this wave's prev-tile ds_reads used),
//     setprio(1) around MFMA clusters. XOR k-chunk swizzle kept
//     (bank-conflict-free, counter-verified). XCD-affinity mapping + nt
//     stores kept from r3.
// ---------------------------------------------------------------------------

typedef __bf16 bf16x8 __attribute__((ext_vector_type(8)));
typedef float  f32x4  __attribute__((ext_vector_type(4)));

#define B_   4
#define T_   256
#define U_   64
#define D_   512
#define K_   512
#define V_   1000
#define ROWS_ 65536L

__device__ __forceinline__ float tanh_fast(float x) {
    float e = __expf(2.0f * x);
    float r = __builtin_amdgcn_rcpf(e + 1.0f);
    return fmaf(-2.0f, r, 1.0f);
}

__device__ __forceinline__ void gl_lds16(const void* g, void* l) {
    __builtin_amdgcn_global_load_lds(
        (const __attribute__((address_space(1))) unsigned int*)g,
        (__attribute__((address_space(3))) unsigned int*)l,
        16, 0, 0);
}

// ---------------- W2 fp32 -> bf16, padded to 1024 rows (zeros) -------------
__global__ __launch_bounds__(256) void w2conv_kernel(const float* __restrict__ W2,
                                                     __bf16* __restrict__ W2b) {
    int idx = (blockIdx.x * 256 + threadIdx.x) * 8;   // over 1024*512 elems
    int v = idx >> 9;
    bf16x8 o;
    if (v < V_) {
        const f32x4* p = (const f32x4*)(W2 + idx);
        f32x4 a = p[0], b = p[1];
#pragma unroll
        for (int j = 0; j < 4; ++j) { o[j] = (__bf16)a[j]; o[4 + j] = (__bf16)b[j]; }
    } else {
#pragma unroll
        for (int j = 0; j < 8; ++j) o[j] = (__bf16)0.0f;
    }
    *(bf16x8*)(W2b + idx) = o;
}

// ---------------- stage 1: he and hd via bf16 MFMA (unchanged, verified) ---
__global__ __launch_bounds__(256) void stage1_kernel(const float* __restrict__ enc,
                                                     const float* __restrict__ dec,
                                                     const float* __restrict__ W1,
                                                     float* __restrict__ he,
                                                     float* __restrict__ hd) {
    const int ct = blockIdx.x;            // k-col tile 0..7
    const int rt = blockIdx.y;            // row tile 0..19
    const bool isDec = rt >= 16;
    const float* X = isDec ? (dec + (rt - 16) * 64 * D_) : (enc + rt * 64 * D_);
    const int   woff = isDec ? D_ : 0;
    float*      Y = isDec ? (hd + (rt - 16) * 64 * K_) : (he + rt * 64 * K_);
    const int   k0 = ct * 64;

    __shared__ __align__(16) __bf16 As[64][72];
    __shared__ __align__(16) __bf16 Bs[64][72];

    const int tid  = threadIdx.x;
    const int lane = tid & 63, w = tid >> 6;
    const int wm = (w >> 1) * 32, wn = (w & 1) * 32;
    const int q = lane >> 4, li = lane & 15;

    f32x4 acc[2][2] = {};

    for (int d0 = 0; d0 < D_; d0 += 64) {
        __syncthreads();
#pragma unroll
        for (int i = 0; i < 2; ++i) {
            int s = tid + i * 256;
            int r = s >> 3, kc = s & 7;
            const f32x4* xp = (const f32x4*)(X + r * D_ + d0 + kc * 8);
            f32x4 x0 = xp[0], x1 = xp[1];
            bf16x8 a;
#pragma unroll
            for (int j = 0; j < 4; ++j) { a[j] = (__bf16)x0[j]; a[4 + j] = (__bf16)x1[j]; }
            *(bf16x8*)&As[r][kc * 8] = a;
            const f32x4* wp = (const f32x4*)(W1 + (k0 + r) * (2 * D_) + woff + d0 + kc * 8);
            f32x4 w0 = wp[0], w1 = wp[1];
            bf16x8 b;
#pragma unroll
            for (int j = 0; j < 4; ++j) { b[j] = (__bf16)w0[j]; b[4 + j] = (__bf16)w1[j]; }
            *(bf16x8*)&Bs[r][kc * 8] = b;
        }
        __syncthreads();
#pragma unroll
        for (int kk = 0; kk < 64; kk += 32) {
            bf16x8 af[2], bfr[2];
#pragma unroll
            for (int mi = 0; mi < 2; ++mi) af[mi]  = *(const bf16x8*)&As[wm + mi * 16 + li][kk + q * 8];
#pragma unroll
            for (int ni = 0; ni < 2; ++ni) bfr[ni] = *(const bf16x8*)&Bs[wn + ni * 16 + li][kk + q * 8];
#pragma unroll
            for (int mi = 0; mi < 2; ++mi)
#pragma unroll
                for (int ni = 0; ni < 2; ++ni)
                    acc[mi][ni] = __builtin_amdgcn_mfma_f32_16x16x32_bf16(af[mi], bfr[ni], acc[mi][ni], 0, 0, 0);
        }
    }
#pragma unroll
    for (int mi = 0; mi < 2; ++mi)
#pragma unroll
        for (int ni = 0; ni < 2; ++ni) {
            int row0 = wm + mi * 16 + q * 4;
            int col  = k0 + wn + ni * 16 + li;
            float* yp = Y + row0 * K_ + col;
            yp[0 * K_] = acc[mi][ni][0];
            yp[1 * K_] = acc[mi][ni][1];
            yp[2 * K_] = acc[mi][ni][2];
            yp[3 * K_] = acc[mi][ni][3];
        }
}

// ---------------- h precompute: tanh(he+hd+b1) -> bf16 ---------------------
// block = 256 threads = 4 rows x 64 k-chunks of 8.
__global__ __launch_bounds__(256) void h_kernel(const float* __restrict__ he,
                                                const float* __restrict__ hd,
                                                const float* __restrict__ b1,
                                                __bf16* __restrict__ h,
                                                long r0) {
    const int tid = threadIdx.x;
    const long rl = (long)blockIdx.x * 4 + (tid >> 6);   // local row in chunk
    const long r  = r0 + rl;                             // global row
    const int  k8 = (tid & 63) * 8;
    const long het = r >> 6;
    const long hdr = (r >> 14) * 64 + (r & 63);
    const f32x4* hp = (const f32x4*)(he + het * K_ + k8);
    const f32x4* dp = (const f32x4*)(hd + hdr * K_ + k8);
    const f32x4* bp = (const f32x4*)(b1 + k8);
    f32x4 s0 = hp[0] + dp[0] + bp[0];
    f32x4 s1 = hp[1] + dp[1] + bp[1];
    bf16x8 o;
#pragma unroll
    for (int j = 0; j < 4; ++j) {
        o[j]     = (__bf16)tanh_fast(s0[j]);
        o[4 + j] = (__bf16)tanh_fast(s1[j]);
    }
    *(bf16x8*)(h + rl * K_ + k8) = o;
}

// ---------------- joint GEMM: C[r,v] = h[r,:] . W2b[v,:] + b2[v] -----------
// BM=256 BN=128 BK=64, counted-vmcnt pipeline.
// LDS: A 3 bufs x [256][64] (96KB) prefetch distance 2;
//      B 2 bufs x [128][64] (32KB) prefetch distance 1.
// Per-thread load ledger (vmcnt units): prologue B0(2) A0(4) A1(4);
// during tile u: B(u+1)(2) then A(u+2)(2+2). Boundary before tile u:
// outstanding = A(u)(4) B(u)(2) A(u+1)(4) -> s_waitcnt vmcnt(4) completes
// A(u),B(u) and leaves A(u+1) in flight. Last tile drains vmcnt(0).
// lgkmcnt(0) before each barrier: guarantees this wave's prev-tile ds_reads
// completed before any wave's post-barrier staging overwrites that buffer
// (A writes at iter u go to (u+2)%3 == (u-1)%3, the buffer read at u-1).
__global__ __launch_bounds__(512, 2) void joint_kernel(const __bf16* __restrict__ h,
                                                       const __bf16* __restrict__ W2b,
                                                       const float* __restrict__ b2,
                                                       float* __restrict__ out,
                                                       long r0, int nrt, int swz) {
    int ct, rt;
    {
        const int d = blockIdx.x;
        if (swz) {
            const int xcd = d & 7;        // HW: dispatch id % 8 == XCD
            const int m   = d >> 3;
            ct = m & 7;                   // 8 consecutive same-XCD ids share rt
            rt = xcd * (nrt >> 3) + (m >> 3);
        } else {
            ct = d & 7;
            rt = d >> 3;
        }
    }

    __shared__ __align__(16) __bf16 As[3 * 256 * 64];   // 96 KB
    __shared__ __align__(16) __bf16 Bs[2 * 128 * 64];   // 32 KB

    const int tid  = threadIdx.x;
    const int lane = tid & 63, w = tid >> 6;
    const int wm = (w & 3) * 64;          // 4 M-waves over 256 rows
    const int wn = (w >> 2) * 64;         // 2 N-waves over 128 cols
    const int q = lane >> 4, li = lane & 15;

    // staging: thread t covers row (j*64 + t>>3), phys chunk (t&7); global
    // k-chunk pre-swizzled so LDS dest stays linear (gl_lds requirement).
    const int tr  = tid >> 3;                        // 0..63
    const int swl = ((tid & 7) ^ (tr & 7)) * 8;      // swizzled k elem offset
    const __bf16* aG = h   + ((long)rt * 256 + tr) * K_ + swl;
    const __bf16* bG = W2b + ((long)ct * 128 + tr) * K_ + swl;
    char* AsC = (char*)As;
    char* BsC = (char*)Bs;
    const int ldsOff = tid * 16;

    // fragment read: row R, logical chunk (q + 4*kk) -> phys ((q ^ (R&7)) ^ 4kk)
    const int csk0 = (q ^ (li & 7)) * 16;

    f32x4 acc[4][4] = {};

    // ---- prologue: issue B(0)(2), A(0)(4), A(1)(4) in this order ----
#pragma unroll
    for (int j = 0; j < 2; ++j)
        gl_lds16(bG + j * 64 * K_, BsC + j * 8192 + ldsOff);
#pragma unroll
    for (int j = 0; j < 4; ++j)
        gl_lds16(aG + j * 64 * K_, AsC + j * 8192 + ldsOff);
#pragma unroll
    for (int j = 0; j < 4; ++j)
        gl_lds16(aG + 64 + j * 64 * K_, AsC + 32768 + j * 8192 + ldsOff);

#pragma unroll
    for (int u = 0; u < 8; ++u) {
        // boundary: tile u's data (A(u),B(u)) complete; A(u+1) stays in flight
        if (u < 7) asm volatile("s_waitcnt vmcnt(4) lgkmcnt(0)" ::: "memory");
        else       asm volatile("s_waitcnt vmcnt(0) lgkmcnt(0)" ::: "memory");
        __builtin_amdgcn_s_barrier();

        const char* Ab = AsC + (u % 3) * 32768;
        const char* Bb = BsC + (u & 1) * 16384;

        // stage B(u+1) first (older than A(u+2) in the vmcnt ledger)
        if (u + 1 < 8) {
#pragma unroll
            for (int j = 0; j < 2; ++j)
                gl_lds16(bG + (u + 1) * 64 + j * 64 * K_,
                         BsC + ((u + 1) & 1) * 16384 + j * 8192 + ldsOff);
        }
        // stage A(u+2) rounds 0,1
        if (u + 2 < 8) {
#pragma unroll
            for (int j = 0; j < 2; ++j)
                gl_lds16(aG + (u + 2) * 64 + j * 64 * K_,
                         AsC + ((u + 2) % 3) * 32768 + j * 8192 + ldsOff);
        }

        // ---- phase A: B frags (kept for both phases) + A frags mi 0,1 ----
        bf16x8 bfr[4][2], af[2][2];
#pragma unroll
        for (int ni = 0; ni < 4; ++ni)
#pragma unroll
            for (int kk = 0; kk < 2; ++kk)
                bfr[ni][kk] = *(const bf16x8*)(Bb + (wn + ni * 16 + li) * 128 + (csk0 ^ (kk << 6)));
#pragma unroll
        for (int mi = 0; mi < 2; ++mi)
#pragma unroll
            for (int kk = 0; kk < 2; ++kk)
                af[mi][kk] = *(const bf16x8*)(Ab + (wm + mi * 16 + li) * 128 + (csk0 ^ (kk << 6)));
        __builtin_amdgcn_s_setprio(1);
#pragma unroll
        for (int kk = 0; kk < 2; ++kk)
#pragma unroll
            for (int mi = 0; mi < 2; ++mi)
#pragma unroll
                for (int ni = 0; ni < 4; ++ni)
                    acc[mi][ni] = __builtin_amdgcn_mfma_f32_16x16x32_bf16(af[mi][kk], bfr[ni][kk], acc[mi][ni], 0, 0, 0);
        __builtin_amdgcn_s_setprio(0);

        // stage A(u+2) rounds 2,3
        if (u + 2 < 8) {
#pragma unroll
            for (int j = 2; j < 4; ++j)
                gl_lds16(aG + (u + 2) * 64 + j * 64 * K_,
                         AsC + ((u + 2) % 3) * 32768 + j * 8192 + ldsOff);
        }

        // ---- phase B: A frags mi 2,3 ----
#pragma unroll
        for (int mi = 0; mi < 2; ++mi)
#pragma unroll
            for (int kk = 0; kk < 2; ++kk)
                af[mi][kk] = *(const bf16x8*)(Ab + (wm + (2 + mi) * 16 + li) * 128 + (csk0 ^ (kk << 6)));
        __builtin_amdgcn_s_setprio(1);
#pragma unroll
        for (int kk = 0; kk < 2; ++kk)
#pragma unroll
            for (int mi = 0; mi < 2; ++mi)
#pragma unroll
                for (int ni = 0; ni < 4; ++ni)
                    acc[2 + mi][ni] = __builtin_amdgcn_mfma_f32_16x16x32_bf16(af[mi][kk], bfr[ni][kk], acc[2 + mi][ni], 0, 0, 0);
        __builtin_amdgcn_s_setprio(0);
    }

    // ---- epilogue ----
    const long rbase = r0 + (long)rt * 256 + wm;
#pragma unroll
    for (int ni = 0; ni < 4; ++ni) {
        int gv = ct * 128 + wn + ni * 16 + li;
        if (gv < V_) {
            float bb = b2[gv];
#pragma unroll
            for (int mi = 0; mi < 4; ++mi) {
                long rr = rbase + mi * 16 + q * 4;
                float* op = out + rr * V_ + gv;
                __builtin_nontemporal_store(acc[mi][ni][0] + bb, op + 0L * V_);
                __builtin_nontemporal_store(acc[mi][ni][1] + bb, op + 1L * V_);
                __builtin_nontemporal_store(acc[mi][ni][2] + bb, op + 2L * V_);
                __builtin_nontemporal_store(acc[mi][ni][3] + bb, op + 3L * V_);
            }
        }
    }
}

extern "C" void kernel_launch(void* const* d_in, const int* in_sizes, int n_in,
                              void* d_out, int out_size, void* d_ws, size_t ws_size,
                              hipStream_t stream) {
    const float* enc = (const float*)d_in[0];   // (4,256,512)
    const float* dec = (const float*)d_in[1];   // (4,64,512)
    const float* W1  = (const float*)d_in[2];   // (512,1024)
    const float* b1  = (const float*)d_in[3];   // (512,)
    const float* W2  = (const float*)d_in[4];   // (1000,512)
    const float* b2  = (const float*)d_in[5];   // (1000,)
    float* out = (float*)d_out;                 // (4,256,64,1000) fp32

    // workspace: he (2MB) | hd (0.5MB) | W2b (1MB, 1024 rows) | h (chunk)
    float*  he  = (float*)d_ws;
    float*  hd  = he + 1024 * K_;
    __bf16* W2b = (__bf16*)(hd + 256 * K_);
    __bf16* h   = W2b + 1024 * K_;
    const size_t fixed = (size_t)(1024 + 256) * K_ * 4 + (size_t)1024 * K_ * 2;

    long chunk = 0;
    if (ws_size > fixed) chunk = (long)((ws_size - fixed) / (K_ * 2));
    if (chunk >= ROWS_) chunk = ROWS_;
    else if (chunk >= 2048) chunk &= ~2047L;    // keep nrt % 8 == 0 for swizzle
    else chunk &= ~255L;                        // BM=256 granularity
    if (chunk < 256) chunk = 256;               // assume ws is at least ~4MB

    w2conv_kernel<<<dim3(256), dim3(256), 0, stream>>>(W2, W2b);
    stage1_kernel<<<dim3(8, 20), dim3(256), 0, stream>>>(enc, dec, W1, he, hd);
    for (long r0 = 0; r0 < ROWS_; r0 += chunk) {
        long rows = ROWS_ - r0 < chunk ? ROWS_ - r0 : chunk;
        int  nrt  = (int)(rows / 256);
        int  swz  = (nrt & 7) == 0 ? 1 : 0;
        h_kernel<<<dim3((int)(rows / 4)), dim3(256), 0, stream>>>(he, hd, b1, h, r0);
        joint_kernel<<<dim3(8 * nrt), dim3(512), 0, stream>>>(h, W2b, b2, out, r0, nrt, swz);
    }
}

// Round 4
// 416.037 us; speedup vs baseline: 1.0629x; 1.0629x over previous
//
#include <hip/hip_runtime.h>

// ---------------------------------------------------------------------------
// Transducer joint network, round 6:
//   = round-3 verified structure (joint 176us) with ONE change:
//     nontemporal output stores -> PLAIN stores.
//   Theory: nt stores bypass L2 write-combining; 4000B output rows make half
//   of all 64B lane-segments straddle cache lines -> partial-line RMW at HBM
//   caps writes at ~1.8 TB/s (measured in BOTH r3 and r5 schedules, while
//   fillBufferAligned does 5.2 TB/s plain). Plain stores restore L2
//   write-combine path.
//   Everything else identical to r3: stage1 MFMA, h precompute, joint
//   128x128/BK=64 gl_lds staging, XOR swizzle (bank-conflict-free,
//   counter-verified 0), XCD-affinity block mapping.
// ---------------------------------------------------------------------------

typedef __bf16 bf16x8 __attribute__((ext_vector_type(8)));
typedef float  f32x4  __attribute__((ext_vector_type(4)));

#define B_   4
#define T_   256
#define U_   64
#define D_   512
#define K_   512
#define V_   1000
#define ROWS_ 65536L

__device__ __forceinline__ float tanh_fast(float x) {
    float e = __expf(2.0f * x);
    float r = __builtin_amdgcn_rcpf(e + 1.0f);
    return fmaf(-2.0f, r, 1.0f);
}

__device__ __forceinline__ void gl_lds16(const void* g, void* l) {
    __builtin_amdgcn_global_load_lds(
        (const __attribute__((address_space(1))) unsigned int*)g,
        (__attribute__((address_space(3))) unsigned int*)l,
        16, 0, 0);
}

// ---------------- W2 fp32 -> bf16, padded to 1024 rows (zeros) -------------
__global__ __launch_bounds__(256) void w2conv_kernel(const float* __restrict__ W2,
                                                     __bf16* __restrict__ W2b) {
    int idx = (blockIdx.x * 256 + threadIdx.x) * 8;   // over 1024*512 elems
    int v = idx >> 9;
    bf16x8 o;
    if (v < V_) {
        const f32x4* p = (const f32x4*)(W2 + idx);
        f32x4 a = p[0], b = p[1];
#pragma unroll
        for (int j = 0; j < 4; ++j) { o[j] = (__bf16)a[j]; o[4 + j] = (__bf16)b[j]; }
    } else {
#pragma unroll
        for (int j = 0; j < 8; ++j) o[j] = (__bf16)0.0f;
    }
    *(bf16x8*)(W2b + idx) = o;
}

// ---------------- stage 1: he and hd via bf16 MFMA (unchanged, verified) ---
__global__ __launch_bounds__(256) void stage1_kernel(const float* __restrict__ enc,
                                                     const float* __restrict__ dec,
                                                     const float* __restrict__ W1,
                                                     float* __restrict__ he,
                                                     float* __restrict__ hd) {
    const int ct = blockIdx.x;            // k-col tile 0..7
    const int rt = blockIdx.y;            // row tile 0..19
    const bool isDec = rt >= 16;
    const float* X = isDec ? (dec + (rt - 16) * 64 * D_) : (enc + rt * 64 * D_);
    const int   woff = isDec ? D_ : 0;
    float*      Y = isDec ? (hd + (rt - 16) * 64 * K_) : (he + rt * 64 * K_);
    const int   k0 = ct * 64;

    __shared__ __align__(16) __bf16 As[64][72];
    __shared__ __align__(16) __bf16 Bs[64][72];

    const int tid  = threadIdx.x;
    const int lane = tid & 63, w = tid >> 6;
    const int wm = (w >> 1) * 32, wn = (w & 1) * 32;
    const int q = lane >> 4, li = lane & 15;

    f32x4 acc[2][2] = {};

    for (int d0 = 0; d0 < D_; d0 += 64) {
        __syncthreads();
#pragma unroll
        for (int i = 0; i < 2; ++i) {
            int s = tid + i * 256;
            int r = s >> 3, kc = s & 7;
            const f32x4* xp = (const f32x4*)(X + r * D_ + d0 + kc * 8);
            f32x4 x0 = xp[0], x1 = xp[1];
            bf16x8 a;
#pragma unroll
            for (int j = 0; j < 4; ++j) { a[j] = (__bf16)x0[j]; a[4 + j] = (__bf16)x1[j]; }
            *(bf16x8*)&As[r][kc * 8] = a;
            const f32x4* wp = (const f32x4*)(W1 + (k0 + r) * (2 * D_) + woff + d0 + kc * 8);
            f32x4 w0 = wp[0], w1 = wp[1];
            bf16x8 b;
#pragma unroll
            for (int j = 0; j < 4; ++j) { b[j] = (__bf16)w0[j]; b[4 + j] = (__bf16)w1[j]; }
            *(bf16x8*)&Bs[r][kc * 8] = b;
        }
        __syncthreads();
#pragma unroll
        for (int kk = 0; kk < 64; kk += 32) {
            bf16x8 af[2], bfr[2];
#pragma unroll
            for (int mi = 0; mi < 2; ++mi) af[mi]  = *(const bf16x8*)&As[wm + mi * 16 + li][kk + q * 8];
#pragma unroll
            for (int ni = 0; ni < 2; ++ni) bfr[ni] = *(const bf16x8*)&Bs[wn + ni * 16 + li][kk + q * 8];
#pragma unroll
            for (int mi = 0; mi < 2; ++mi)
#pragma unroll
                for (int ni = 0; ni < 2; ++ni)
                    acc[mi][ni] = __builtin_amdgcn_mfma_f32_16x16x32_bf16(af[mi], bfr[ni], acc[mi][ni], 0, 0, 0);
        }
    }
#pragma unroll
    for (int mi = 0; mi < 2; ++mi)
#pragma unroll
        for (int ni = 0; ni < 2; ++ni) {
            int row0 = wm + mi * 16 + q * 4;
            int col  = k0 + wn + ni * 16 + li;
            float* yp = Y + row0 * K_ + col;
            yp[0 * K_] = acc[mi][ni][0];
            yp[1 * K_] = acc[mi][ni][1];
            yp[2 * K_] = acc[mi][ni][2];
            yp[3 * K_] = acc[mi][ni][3];
        }
}

// ---------------- h precompute: tanh(he+hd+b1) -> bf16 ---------------------
// block = 256 threads = 4 rows x 64 k-chunks of 8.
__global__ __launch_bounds__(256) void h_kernel(const float* __restrict__ he,
                                                const float* __restrict__ hd,
                                                const float* __restrict__ b1,
                                                __bf16* __restrict__ h,
                                                long r0) {
    const int tid = threadIdx.x;
    const long rl = (long)blockIdx.x * 4 + (tid >> 6);   // local row in chunk
    const long r  = r0 + rl;                             // global row
    const int  k8 = (tid & 63) * 8;
    const long het = r >> 6;
    const long hdr = (r >> 14) * 64 + (r & 63);
    const f32x4* hp = (const f32x4*)(he + het * K_ + k8);
    const f32x4* dp = (const f32x4*)(hd + hdr * K_ + k8);
    const f32x4* bp = (const f32x4*)(b1 + k8);
    f32x4 s0 = hp[0] + dp[0] + bp[0];
    f32x4 s1 = hp[1] + dp[1] + bp[1];
    bf16x8 o;
#pragma unroll
    for (int j = 0; j < 4; ++j) {
        o[j]     = (__bf16)tanh_fast(s0[j]);
        o[4 + j] = (__bf16)tanh_fast(s1[j]);
    }
    *(bf16x8*)(h + rl * K_ + k8) = o;
}

// ---------------- joint GEMM: C[r,v] = h[r,:] . W2b[v,:] + b2[v] -----------
// 128x128 tile, BK=64, global_load_lds staging, XOR chunk swizzle.
// 1-D grid with XCD-affinity mapping: dispatch id d -> XCD d&7 (HW round
// robin). 8 consecutive same-XCD ids are the 8 ct tiles of one rt: A panel
// (128 rows of h) is fetched into that XCD's L2 once and shared.
__global__ __launch_bounds__(256) void joint_kernel(const __bf16* __restrict__ h,
                                                    const __bf16* __restrict__ W2b,
                                                    const float* __restrict__ b2,
                                                    float* __restrict__ out,
                                                    long r0, int nrt, int swz) {
    int ct, rt;
    {
        const int d = blockIdx.x;
        if (swz) {
            const int xcd = d & 7;        // HW: dispatch id % 8 == XCD
            const int m   = d >> 3;
            ct = m & 7;
            rt = xcd * (nrt >> 3) + (m >> 3);
        } else {
            ct = d & 7;
            rt = d >> 3;
        }
    }

    __shared__ __align__(16) __bf16 As[128 * 64];
    __shared__ __align__(16) __bf16 Bs[128 * 64];

    const int tid  = threadIdx.x;
    const int lane = tid & 63, w = tid >> 6;
    const int wm = (w >> 1) * 64, wn = (w & 1) * 64;
    const int q = lane >> 4, li = lane & 15;

    // staging: lane l of wave w, issue i covers LDS row i*32 + w*8 + (l>>3),
    // LDS chunk (l&7); global k-chunk is XOR-swizzled.
    const int srow = lane >> 3;
    const int scol = ((lane & 7) ^ (srow & 7)) * 8;     // swizzled k offset
    const long aRow = (long)rt * 128 + w * 8 + srow;    // + i*32
    const long bRow = (long)ct * 128 + w * 8 + srow;    // + i*32
    const __bf16* aBase = h   + aRow * K_ + scol;
    const __bf16* bBase = W2b + bRow * K_ + scol;
    __bf16* aLds = As + w * 512;                        // + i*2048 (elems)
    __bf16* bLds = Bs + w * 512;

    // fragment read: row R = wm|wn + t*16 + li, byte addr R*128 + cswz
    const int cswz0 = ((q ^ (li & 7)) * 16);            // kk=0 chunk byte off
    const char* AsB = (const char*)As;
    const char* BsB = (const char*)Bs;

    f32x4 acc[4][4] = {};

    for (int k0 = 0; k0 < K_; k0 += 64) {
        __syncthreads();
#pragma unroll
        for (int i = 0; i < 4; ++i) {
            gl_lds16(aBase + (long)i * 32 * K_ + k0, aLds + i * 2048);
            gl_lds16(bBase + (long)i * 32 * K_ + k0, bLds + i * 2048);
        }
        __syncthreads();
#pragma unroll
        for (int kk = 0; kk < 2; ++kk) {
            const int cs = cswz0 ^ (kk << 6);
            bf16x8 af[4], bfr[4];
#pragma unroll
            for (int mi = 0; mi < 4; ++mi) af[mi]  = *(const bf16x8*)(AsB + (wm + mi * 16 + li) * 128 + cs);
#pragma unroll
            for (int ni = 0; ni < 4; ++ni) bfr[ni] = *(const bf16x8*)(BsB + (wn + ni * 16 + li) * 128 + cs);
#pragma unroll
            for (int mi = 0; mi < 4; ++mi)
#pragma unroll
                for (int ni = 0; ni < 4; ++ni)
                    acc[mi][ni] = __builtin_amdgcn_mfma_f32_16x16x32_bf16(af[mi], bfr[ni], acc[mi][ni], 0, 0, 0);
        }
    }

    const long rbase = r0 + (long)rt * 128 + wm;
#pragma unroll
    for (int ni = 0; ni < 4; ++ni) {
        int gv = ct * 128 + wn + ni * 16 + li;
        if (gv < V_) {
            float bb = b2[gv];
#pragma unroll
            for (int mi = 0; mi < 4; ++mi) {
                long rr = rbase + mi * 16 + q * 4;
                float* op = out + rr * V_ + gv;
                // PLAIN stores (r6 change): go through L2 write-combining so
                // 32B-misaligned 64B segments merge into full dirty lines.
                op[0L * V_] = acc[mi][ni][0] + bb;
                op[1L * V_] = acc[mi][ni][1] + bb;
                op[2L * V_] = acc[mi][ni][2] + bb;
                op[3L * V_] = acc[mi][ni][3] + bb;
            }
        }
    }
}

extern "C" void kernel_launch(void* const* d_in, const int* in_sizes, int n_in,
                              void* d_out, int out_size, void* d_ws, size_t ws_size,
                              hipStream_t stream) {
    const float* enc = (const float*)d_in[0];   // (4,256,512)
    const float* dec = (const float*)d_in[1];   // (4,64,512)
    const float* W1  = (const float*)d_in[2];   // (512,1024)
    const float* b1  = (const float*)d_in[3];   // (512,)
    const float* W2  = (const float*)d_in[4];   // (1000,512)
    const float* b2  = (const float*)d_in[5];   // (1000,)
    float* out = (float*)d_out;                 // (4,256,64,1000) fp32

    // workspace: he (2MB) | hd (0.5MB) | W2b (1MB, 1024 rows) | h (chunk)
    float*  he  = (float*)d_ws;
    float*  hd  = he + 1024 * K_;
    __bf16* W2b = (__bf16*)(hd + 256 * K_);
    __bf16* h   = W2b + 1024 * K_;
    const size_t fixed = (size_t)(1024 + 256) * K_ * 4 + (size_t)1024 * K_ * 2;

    long chunk = 0;
    if (ws_size > fixed) chunk = (long)((ws_size - fixed) / (K_ * 2));
    if (chunk >= ROWS_) chunk = ROWS_;
    else if (chunk >= 1024) chunk &= ~1023L;    // keep nrt % 8 == 0 for swizzle
    else chunk &= ~127L;
    if (chunk < 128) chunk = 128;               // assume ws is at least ~4MB

    w2conv_kernel<<<dim3(256), dim3(256), 0, stream>>>(W2, W2b);
    stage1_kernel<<<dim3(8, 20), dim3(256), 0, stream>>>(enc, dec, W1, he, hd);
    for (long r0 = 0; r0 < ROWS_; r0 += chunk) {
        long rows = ROWS_ - r0 < chunk ? ROWS_ - r0 : chunk;
        int  nrt  = (int)(rows / 128);
        int  swz  = (nrt & 7) == 0 ? 1 : 0;
        h_kernel<<<dim3((int)(rows / 4)), dim3(256), 0, stream>>>(he, hd, b1, h, r0);
        joint_kernel<<<dim3(8 * nrt), dim3(256), 0, stream>>>(h, W2b, b2, out, r0, nrt, swz);
    }
}

// Round 5
// 401.865 us; speedup vs baseline: 1.1004x; 1.0353x over previous
//
#include <hip/hip_runtime.h>

// ---------------------------------------------------------------------------
// Transducer joint network, round 7:
//   Theory: joint is HBM-write-efficiency-bound (~2 TB/s on 512B-per-row
//   scattered fp32 output). Changes (joint only):
//     1. BN 128 -> 256 (ct tiles 8 -> 4): 1KB sequential per row-visit,
//        half the B refetch, 2x arithmetic intensity per staged byte.
//     2. MFMA operand swap (mfma(b,a,acc) = C^T fragments): lane holds 4
//        CONSECUTIVE v values -> dwordx4 epilogue stores (4x fewer store
//        instrs), b2 applied as f32x4.
//   Kept verified pieces: gl_lds(16B) staging, XOR k-chunk swizzle (0 bank
//   conflicts), XCD-affinity mapping (4 same-XCD ids = 4 ct of one rt),
//   plain stores, shallow 2-barrier K-loop, stage1/h/w2conv unchanged.
// ---------------------------------------------------------------------------

typedef __bf16 bf16x8 __attribute__((ext_vector_type(8)));
typedef float  f32x4  __attribute__((ext_vector_type(4)));

#define B_   4
#define T_   256
#define U_   64
#define D_   512
#define K_   512
#define V_   1000
#define ROWS_ 65536L

__device__ __forceinline__ float tanh_fast(float x) {
    float e = __expf(2.0f * x);
    float r = __builtin_amdgcn_rcpf(e + 1.0f);
    return fmaf(-2.0f, r, 1.0f);
}

__device__ __forceinline__ void gl_lds16(const void* g, void* l) {
    __builtin_amdgcn_global_load_lds(
        (const __attribute__((address_space(1))) unsigned int*)g,
        (__attribute__((address_space(3))) unsigned int*)l,
        16, 0, 0);
}

// ---------------- W2 fp32 -> bf16, padded to 1024 rows (zeros) -------------
__global__ __launch_bounds__(256) void w2conv_kernel(const float* __restrict__ W2,
                                                     __bf16* __restrict__ W2b) {
    int idx = (blockIdx.x * 256 + threadIdx.x) * 8;   // over 1024*512 elems
    int v = idx >> 9;
    bf16x8 o;
    if (v < V_) {
        const f32x4* p = (const f32x4*)(W2 + idx);
        f32x4 a = p[0], b = p[1];
#pragma unroll
        for (int j = 0; j < 4; ++j) { o[j] = (__bf16)a[j]; o[4 + j] = (__bf16)b[j]; }
    } else {
#pragma unroll
        for (int j = 0; j < 8; ++j) o[j] = (__bf16)0.0f;
    }
    *(bf16x8*)(W2b + idx) = o;
}

// ---------------- stage 1: he and hd via bf16 MFMA (unchanged, verified) ---
__global__ __launch_bounds__(256) void stage1_kernel(const float* __restrict__ enc,
                                                     const float* __restrict__ dec,
                                                     const float* __restrict__ W1,
                                                     float* __restrict__ he,
                                                     float* __restrict__ hd) {
    const int ct = blockIdx.x;            // k-col tile 0..7
    const int rt = blockIdx.y;            // row tile 0..19
    const bool isDec = rt >= 16;
    const float* X = isDec ? (dec + (rt - 16) * 64 * D_) : (enc + rt * 64 * D_);
    const int   woff = isDec ? D_ : 0;
    float*      Y = isDec ? (hd + (rt - 16) * 64 * K_) : (he + rt * 64 * K_);
    const int   k0 = ct * 64;

    __shared__ __align__(16) __bf16 As[64][72];
    __shared__ __align__(16) __bf16 Bs[64][72];

    const int tid  = threadIdx.x;
    const int lane = tid & 63, w = tid >> 6;
    const int wm = (w >> 1) * 32, wn = (w & 1) * 32;
    const int q = lane >> 4, li = lane & 15;

    f32x4 acc[2][2] = {};

    for (int d0 = 0; d0 < D_; d0 += 64) {
        __syncthreads();
#pragma unroll
        for (int i = 0; i < 2; ++i) {
            int s = tid + i * 256;
            int r = s >> 3, kc = s & 7;
            const f32x4* xp = (const f32x4*)(X + r * D_ + d0 + kc * 8);
            f32x4 x0 = xp[0], x1 = xp[1];
            bf16x8 a;
#pragma unroll
            for (int j = 0; j < 4; ++j) { a[j] = (__bf16)x0[j]; a[4 + j] = (__bf16)x1[j]; }
            *(bf16x8*)&As[r][kc * 8] = a;
            const f32x4* wp = (const f32x4*)(W1 + (k0 + r) * (2 * D_) + woff + d0 + kc * 8);
            f32x4 w0 = wp[0], w1 = wp[1];
            bf16x8 b;
#pragma unroll
            for (int j = 0; j < 4; ++j) { b[j] = (__bf16)w0[j]; b[4 + j] = (__bf16)w1[j]; }
            *(bf16x8*)&Bs[r][kc * 8] = b;
        }
        __syncthreads();
#pragma unroll
        for (int kk = 0; kk < 64; kk += 32) {
            bf16x8 af[2], bfr[2];
#pragma unroll
            for (int mi = 0; mi < 2; ++mi) af[mi]  = *(const bf16x8*)&As[wm + mi * 16 + li][kk + q * 8];
#pragma unroll
            for (int ni = 0; ni < 2; ++ni) bfr[ni] = *(const bf16x8*)&Bs[wn + ni * 16 + li][kk + q * 8];
#pragma unroll
            for (int mi = 0; mi < 2; ++mi)
#pragma unroll
                for (int ni = 0; ni < 2; ++ni)
                    acc[mi][ni] = __builtin_amdgcn_mfma_f32_16x16x32_bf16(af[mi], bfr[ni], acc[mi][ni], 0, 0, 0);
        }
    }
#pragma unroll
    for (int mi = 0; mi < 2; ++mi)
#pragma unroll
        for (int ni = 0; ni < 2; ++ni) {
            int row0 = wm + mi * 16 + q * 4;
            int col  = k0 + wn + ni * 16 + li;
            float* yp = Y + row0 * K_ + col;
            yp[0 * K_] = acc[mi][ni][0];
            yp[1 * K_] = acc[mi][ni][1];
            yp[2 * K_] = acc[mi][ni][2];
            yp[3 * K_] = acc[mi][ni][3];
        }
}

// ---------------- h precompute: tanh(he+hd+b1) -> bf16 ---------------------
// block = 256 threads = 4 rows x 64 k-chunks of 8.
__global__ __launch_bounds__(256) void h_kernel(const float* __restrict__ he,
                                                const float* __restrict__ hd,
                                                const float* __restrict__ b1,
                                                __bf16* __restrict__ h,
                                                long r0) {
    const int tid = threadIdx.x;
    const long rl = (long)blockIdx.x * 4 + (tid >> 6);   // local row in chunk
    const long r  = r0 + rl;                             // global row
    const int  k8 = (tid & 63) * 8;
    const long het = r >> 6;
    const long hdr = (r >> 14) * 64 + (r & 63);
    const f32x4* hp = (const f32x4*)(he + het * K_ + k8);
    const f32x4* dp = (const f32x4*)(hd + hdr * K_ + k8);
    const f32x4* bp = (const f32x4*)(b1 + k8);
    f32x4 s0 = hp[0] + dp[0] + bp[0];
    f32x4 s1 = hp[1] + dp[1] + bp[1];
    bf16x8 o;
#pragma unroll
    for (int j = 0; j < 4; ++j) {
        o[j]     = (__bf16)tanh_fast(s0[j]);
        o[4 + j] = (__bf16)tanh_fast(s1[j]);
    }
    *(bf16x8*)(h + rl * K_ + k8) = o;
}

// ---------------- joint GEMM: C[r,v] = h[r,:] . W2b[v,:] + b2[v] -----------
// BM=128, BN=256, BK=64, 256 threads (4 waves: wm=(w>>1)*64, wn=(w&1)*128).
// SWAPPED MFMA operands: acc = C^T fragments (rows=v, cols=r) -> each lane's
// f32x4 is 4 consecutive v of one output row -> dwordx4 stores.
// XCD-affinity: 4 consecutive same-XCD dispatch ids = the 4 ct tiles of one
// rt (A panel fetched once per XCD L2).
__global__ __launch_bounds__(256, 2) void joint_kernel(const __bf16* __restrict__ h,
                                                       const __bf16* __restrict__ W2b,
                                                       const float* __restrict__ b2,
                                                       float* __restrict__ out,
                                                       long r0, int nrt, int swz) {
    int ct, rt;
    {
        const int d = blockIdx.x;
        if (swz) {
            const int xcd = d & 7;        // HW: dispatch id % 8 == XCD
            const int m   = d >> 3;
            ct = m & 3;                   // 4 same-XCD ids share one rt
            rt = xcd * (nrt >> 3) + (m >> 2);
        } else {
            ct = d & 3;
            rt = d >> 2;
        }
    }

    __shared__ __align__(16) __bf16 As[128 * 64];       // 16 KB
    __shared__ __align__(16) __bf16 Bs[256 * 64];       // 32 KB

    const int tid  = threadIdx.x;
    const int lane = tid & 63, w = tid >> 6;
    const int wm = (w >> 1) * 64;         // 2 M-wave rows over 128
    const int wn = (w & 1) * 128;         // 2 N-wave cols over 256
    const int q = lane >> 4, li = lane & 15;

    // staging: lane l of wave w, issue i covers LDS row i*32 + w*8 + (l>>3),
    // LDS chunk (l&7); global k-chunk is XOR-swizzled.
    const int srow = lane >> 3;
    const int scol = ((lane & 7) ^ (srow & 7)) * 8;     // swizzled k offset
    const long aRow = (long)rt * 128 + w * 8 + srow;    // + i*32, i<4
    const long bRow = (long)ct * 256 + w * 8 + srow;    // + i*32, i<8
    const __bf16* aBase = h   + aRow * K_ + scol;
    const __bf16* bBase = W2b + bRow * K_ + scol;
    __bf16* aLds = As + w * 512;                        // + i*2048 (elems)
    __bf16* bLds = Bs + w * 512;

    // fragment read: row R = (wm|wn) + t*16 + li, byte addr R*128 + cswz
    const int cswz0 = ((q ^ (li & 7)) * 16);            // kk=0 chunk byte off
    const char* AsB = (const char*)As;
    const char* BsB = (const char*)Bs;

    f32x4 acc[8][4] = {};                               // [ni][mi], C^T frags

    for (int k0 = 0; k0 < K_; k0 += 64) {
        __syncthreads();
#pragma unroll
        for (int i = 0; i < 4; ++i)
            gl_lds16(aBase + (long)i * 32 * K_ + k0, aLds + i * 2048);
#pragma unroll
        for (int i = 0; i < 8; ++i)
            gl_lds16(bBase + (long)i * 32 * K_ + k0, bLds + i * 2048);
        __syncthreads();
#pragma unroll
        for (int kk = 0; kk < 2; ++kk) {
            const int cs = cswz0 ^ (kk << 6);
            bf16x8 af[4], bfr[8];
#pragma unroll
            for (int mi = 0; mi < 4; ++mi) af[mi]  = *(const bf16x8*)(AsB + (wm + mi * 16 + li) * 128 + cs);
#pragma unroll
            for (int ni = 0; ni < 8; ++ni) bfr[ni] = *(const bf16x8*)(BsB + (wn + ni * 16 + li) * 128 + cs);
#pragma unroll
            for (int ni = 0; ni < 8; ++ni)
#pragma unroll
                for (int mi = 0; mi < 4; ++mi)
                    acc[ni][mi] = __builtin_amdgcn_mfma_f32_16x16x32_bf16(bfr[ni], af[mi], acc[ni][mi], 0, 0, 0);
        }
    }

    // epilogue: acc[ni][mi][j] = C[r = rb + mi*16 + li][v = v0(ni) + j]
    const long rb = r0 + (long)rt * 128 + wm;
#pragma unroll
    for (int ni = 0; ni < 8; ++ni) {
        int v0 = ct * 256 + wn + ni * 16 + q * 4;
        if (v0 < V_) {                     // v0 % 4 == 0 -> v0 <= 996, x4 safe
            f32x4 bv = *(const f32x4*)(b2 + v0);
#pragma unroll
            for (int mi = 0; mi < 4; ++mi) {
                long r = rb + mi * 16 + li;
                *(f32x4*)(out + r * V_ + v0) = acc[ni][mi] + bv;
            }
        }
    }
}

extern "C" void kernel_launch(void* const* d_in, const int* in_sizes, int n_in,
                              void* d_out, int out_size, void* d_ws, size_t ws_size,
                              hipStream_t stream) {
    const float* enc = (const float*)d_in[0];   // (4,256,512)
    const float* dec = (const float*)d_in[1];   // (4,64,512)
    const float* W1  = (const float*)d_in[2];   // (512,1024)
    const float* b1  = (const float*)d_in[3];   // (512,)
    const float* W2  = (const float*)d_in[4];   // (1000,512)
    const float* b2  = (const float*)d_in[5];   // (1000,)
    float* out = (float*)d_out;                 // (4,256,64,1000) fp32

    // workspace: he (2MB) | hd (0.5MB) | W2b (1MB, 1024 rows) | h (chunk)
    float*  he  = (float*)d_ws;
    float*  hd  = he + 1024 * K_;
    __bf16* W2b = (__bf16*)(hd + 256 * K_);
    __bf16* h   = W2b + 1024 * K_;
    const size_t fixed = (size_t)(1024 + 256) * K_ * 4 + (size_t)1024 * K_ * 2;

    long chunk = 0;
    if (ws_size > fixed) chunk = (long)((ws_size - fixed) / (K_ * 2));
    if (chunk >= ROWS_) chunk = ROWS_;
    else if (chunk >= 1024) chunk &= ~1023L;    // keep nrt % 8 == 0 for swizzle
    else chunk &= ~127L;
    if (chunk < 128) chunk = 128;               // assume ws is at least ~4MB

    w2conv_kernel<<<dim3(256), dim3(256), 0, stream>>>(W2, W2b);
    stage1_kernel<<<dim3(8, 20), dim3(256), 0, stream>>>(enc, dec, W1, he, hd);
    for (long r0 = 0; r0 < ROWS_; r0 += chunk) {
        long rows = ROWS_ - r0 < chunk ? ROWS_ - r0 : chunk;
        int  nrt  = (int)(rows / 128);
        int  swz  = (nrt & 7) == 0 ? 1 : 0;
        h_kernel<<<dim3((int)(rows / 4)), dim3(256), 0, stream>>>(he, hd, b1, h, r0);
        joint_kernel<<<dim3(4 * nrt), dim3(256), 0, stream>>>(h, W2b, b2, out, r0, nrt, swz);
    }
}